// Round 1
// baseline (2830.842 us; speedup 1.0000x reference)
//
#include <hip/hip_runtime.h>
#include <hip/hip_bf16.h>

#define EPSF 1e-5f

// ---------------------------------------------------------------------------
// Generic fp32 GEMM: C[bz] (MxN, ldC) = op( W[bz] (MxK, row-major) * X[bz] (KxN) )
// mode 0: plain store
// mode 1: per-row BN (+ReLU): bn = [4][M] rows g,b,mean,var
// mode 2: per-column scale: colscale[bz*N + col]
// Tile 128x128, BK=16, 256 threads, 8x8 micro-tile as 2x2 blocks of 4x4.
// Requires M%128==0, N%128==0, K%16==0 (true for all uses here).
// ---------------------------------------------------------------------------
__global__ __launch_bounds__(256) void gemm_f32(
    const float* __restrict__ W, long wbs,
    const float* __restrict__ X, long xbs,
    float* __restrict__ C, long cbs, int ldC,
    int M, int N, int K,
    const float* __restrict__ bn,
    const float* __restrict__ colscale,
    int mode)
{
    __shared__ float Ws[16][132];
    __shared__ float Xs[16][132];

    const int tid = threadIdx.x;
    const int tx = tid & 15;
    const int ty = tid >> 4;
    const int row0 = blockIdx.y * 128;
    const int col0 = blockIdx.x * 128;
    const int bz = blockIdx.z;

    const float* Wb = W + (long)bz * wbs;
    const float* Xb = X + (long)bz * xbs;

    float acc[8][8];
#pragma unroll
    for (int i = 0; i < 8; ++i)
#pragma unroll
        for (int j = 0; j < 8; ++j) acc[i][j] = 0.f;

    for (int k0 = 0; k0 < K; k0 += 16) {
        // W tile: 128 rows x 16 k (scalar loads, 8 per thread), stored transposed
#pragma unroll
        for (int r = 0; r < 8; ++r) {
            int idx = tid + r * 256;
            int wr = idx >> 4;      // 0..127
            int wk = idx & 15;      // 0..15
            Ws[wk][wr] = Wb[(long)(row0 + wr) * K + (k0 + wk)];
        }
        // X tile: 16 k x 128 cols (float4 loads, 2 per thread)
#pragma unroll
        for (int r = 0; r < 2; ++r) {
            int idx4 = tid + r * 256;
            int xk = idx4 >> 5;            // 0..15
            int xc = (idx4 & 31) << 2;     // 0..124
            *reinterpret_cast<float4*>(&Xs[xk][xc]) =
                *reinterpret_cast<const float4*>(&Xb[(long)(k0 + xk) * N + (col0 + xc)]);
        }
        __syncthreads();
#pragma unroll
        for (int kk = 0; kk < 16; ++kk) {
            float4 a0 = *reinterpret_cast<const float4*>(&Ws[kk][ty * 4]);
            float4 a1 = *reinterpret_cast<const float4*>(&Ws[kk][64 + ty * 4]);
            float4 b0 = *reinterpret_cast<const float4*>(&Xs[kk][tx * 4]);
            float4 b1 = *reinterpret_cast<const float4*>(&Xs[kk][64 + tx * 4]);
            float av[8] = {a0.x, a0.y, a0.z, a0.w, a1.x, a1.y, a1.z, a1.w};
            float bv[8] = {b0.x, b0.y, b0.z, b0.w, b1.x, b1.y, b1.z, b1.w};
#pragma unroll
            for (int i = 0; i < 8; ++i)
#pragma unroll
                for (int j = 0; j < 8; ++j)
                    acc[i][j] = fmaf(av[i], bv[j], acc[i][j]);
        }
        __syncthreads();
    }

    float* Cb = C + (long)bz * cbs;
#pragma unroll
    for (int i = 0; i < 8; ++i) {
        int r = row0 + ((i < 4) ? (ty * 4 + i) : (64 + ty * 4 + (i - 4)));
        float sc = 1.f, off = 0.f;
        if (mode == 1) {
            float g  = bn[r];
            float bb = bn[M + r];
            float mm = bn[2 * M + r];
            float vv = bn[3 * M + r];
            sc  = g / sqrtf(vv + EPSF);
            off = bb - mm * sc;
        }
        int c0a = col0 + tx * 4;
        int c0b = col0 + 64 + tx * 4;
        float4 va, vb2;
        float* pa = &va.x;
        float* pb = &vb2.x;
#pragma unroll
        for (int j = 0; j < 4; ++j) {
            float v = acc[i][j];
            if (mode == 1) { v = fmaf(v, sc, off); v = fmaxf(v, 0.f); }
            pa[j] = v;
        }
#pragma unroll
        for (int j = 0; j < 4; ++j) {
            float v = acc[i][4 + j];
            if (mode == 1) { v = fmaf(v, sc, off); v = fmaxf(v, 0.f); }
            pb[j] = v;
        }
        if (mode == 2) {
            float4 s0 = *reinterpret_cast<const float4*>(&colscale[(long)bz * N + c0a]);
            float4 s1 = *reinterpret_cast<const float4*>(&colscale[(long)bz * N + c0b]);
            va.x *= s0.x; va.y *= s0.y; va.z *= s0.z; va.w *= s0.w;
            vb2.x *= s1.x; vb2.y *= s1.y; vb2.z *= s1.z; vb2.w *= s1.w;
        }
        *reinterpret_cast<float4*>(&Cb[(long)r * ldC + c0a]) = va;
        *reinterpret_cast<float4*>(&Cb[(long)r * ldC + c0b]) = vb2;
    }
}

// ---------------------------------------------------------------------------
// Column softmax stats (over c for each (n,t)), split into CS chunks over C.
// Block: 256 threads = 64 t-columns x 4 c-groups. Grid: (T/64, CS, nb)
// ---------------------------------------------------------------------------
__global__ __launch_bounds__(256) void softmax_partial(
    const float* __restrict__ A,  // [nb][C][T]
    float* __restrict__ pmax,     // [nb][CS][T]
    float* __restrict__ psum,     // [nb][CS][T]
    int C, int T, int CS)
{
    int n = blockIdx.z;
    int tl = threadIdx.x & 63;
    int t = blockIdx.x * 64 + tl;
    int cg = threadIdx.x >> 6;  // 0..3
    int chunkLen = C / CS;
    int cBeg = blockIdx.y * chunkLen;
    int cEnd = cBeg + chunkLen;
    const float* Ab = A + (long)n * C * T;

    float m = -3.0e38f, s = 0.f;
    for (int c = cBeg + cg; c < cEnd; c += 4) {
        float v = Ab[(long)c * T + t];
        float mn = fmaxf(m, v);
        s = s * __expf(m - mn) + __expf(v - mn);
        m = mn;
    }
    __shared__ float sm[4][64];
    __shared__ float ss[4][64];
    sm[cg][tl] = m;
    ss[cg][tl] = s;
    __syncthreads();
    if (cg == 0) {
        float M0 = sm[0][tl], S0 = ss[0][tl];
#pragma unroll
        for (int i = 1; i < 4; ++i) {
            float mi = sm[i][tl], si = ss[i][tl];
            float mn = fmaxf(M0, mi);
            S0 = S0 * __expf(M0 - mn) + si * __expf(mi - mn);
            M0 = mn;
        }
        long o = ((long)n * CS + blockIdx.y) * T + t;
        pmax[o] = M0;
        psum[o] = S0;
    }
}

__global__ __launch_bounds__(256) void softmax_combine(
    const float* __restrict__ pmax, const float* __restrict__ psum,
    float* __restrict__ colmax, float* __restrict__ colrsum, int T, int CS)
{
    long idx = (long)blockIdx.x * blockDim.x + threadIdx.x;  // over nb*T
    int n = (int)(idx / T);
    int t = (int)(idx % T);
    float M = -3.0e38f, S = 0.f;
    for (int i = 0; i < CS; ++i) {
        long o = ((long)n * CS + i) * T + t;
        float mi = pmax[o], si = psum[o];
        float mn = fmaxf(M, mi);
        S = S * __expf(M - mn) + si * __expf(mi - mn);
        M = mn;
    }
    colmax[idx] = M;
    colrsum[idx] = 1.0f / S;
}

// E = exp(a - colmax[t]) in place; float4 grid-stride. T must be power of 2.
__global__ __launch_bounds__(256) void softmax_expwrite(
    float* __restrict__ A, const float* __restrict__ colmax,
    int C, int T, long total4)
{
    long i4 = (long)blockIdx.x * blockDim.x + threadIdx.x;
    long stride = (long)gridDim.x * blockDim.x;
    for (; i4 < total4; i4 += stride) {
        long base = i4 * 4;
        int t = (int)(base & (long)(T - 1));
        int n = (int)(base / ((long)C * T));
        float4 v = *reinterpret_cast<const float4*>(&A[base]);
        float4 m = *reinterpret_cast<const float4*>(&colmax[(long)n * T + t]);
        v.x = __expf(v.x - m.x);
        v.y = __expf(v.y - m.y);
        v.z = __expf(v.z - m.z);
        v.w = __expf(v.w - m.w);
        *reinterpret_cast<float4*>(&A[base]) = v;
    }
}

// ---------------------------------------------------------------------------
extern "C" void kernel_launch(void* const* d_in, const int* in_sizes, int n_in,
                              void* d_out, int out_size, void* d_ws, size_t ws_size,
                              hipStream_t stream)
{
    const int NB = 2, CIN = 2048, HW = 4096, RC = 512, CT = 4096;
    const float* x = (const float*)d_in[0];

    float* ws = (float*)d_ws;
    float* red    = ws;                                 // NB*RC*HW
    float* a1     = red    + (long)NB * RC * HW;        // NB*RC*HW
    float* logits = a1     + (long)NB * RC * HW;        // NB*CT*HW
    float* pmax   = logits + (long)NB * CT * HW;        // NB*4*HW
    float* psum   = pmax   + (long)NB * 4 * HW;         // NB*4*HW
    float* colmax = psum   + (long)NB * 4 * HW;         // NB*HW
    float* colrsum= colmax + (long)NB * HW;             // NB*HW

    dim3 blk(256);

    for (int br = 0; br < 2; ++br) {
        const float* w_red = (const float*)d_in[1 + br * 5 + 0];
        const float* bn1   = (const float*)d_in[1 + br * 5 + 1];
        const float* w1    = (const float*)d_in[1 + br * 5 + 2];
        const float* bn2   = (const float*)d_in[1 + br * 5 + 3];
        const float* w2    = (const float*)d_in[1 + br * 5 + 4];

        // conv_reduce + BN1 + ReLU: red[n] = relu(bn(w_red * x[n]))
        gemm_f32<<<dim3(HW / 128, RC / 128, NB), blk, 0, stream>>>(
            w_red, 0, x, (long)CIN * HW, red, (long)RC * HW, HW,
            RC, HW, CIN, bn1, nullptr, 1);

        // conv1 + BN2 + ReLU: a1[n] = relu(bn(w1 * red[n]))
        gemm_f32<<<dim3(HW / 128, RC / 128, NB), blk, 0, stream>>>(
            w1, 0, red, (long)RC * HW, a1, (long)RC * HW, HW,
            RC, HW, RC, bn2, nullptr, 1);

        // conv2: logits[n] = w2 * a1[n]
        gemm_f32<<<dim3(HW / 128, CT / 128, NB), blk, 0, stream>>>(
            w2, 0, a1, (long)RC * HW, logits, (long)CT * HW, HW,
            CT, HW, RC, nullptr, nullptr, 0);

        // column softmax stats over c
        softmax_partial<<<dim3(HW / 64, 4, NB), blk, 0, stream>>>(
            logits, pmax, psum, CT, HW, 4);
        softmax_combine<<<dim3(NB * HW / 256), blk, 0, stream>>>(
            pmax, psum, colmax, colrsum, HW, 4);
        // E = exp(logits - colmax) in place
        softmax_expwrite<<<dim3(2048), blk, 0, stream>>>(
            logits, colmax, CT, HW, (long)NB * CT * HW / 4);

        // fm = red @ E, column-scaled by 1/sum -> write into output concat slice
        float* outb = (float*)d_out + (long)br * RC * HW;
        gemm_f32<<<dim3(HW / 128, RC / 128, NB), blk, 0, stream>>>(
            red, (long)RC * HW, logits, (long)CT * HW, outb, (long)2 * RC * HW, HW,
            RC, HW, CT, nullptr, colrsum, 2);
    }
}

// Round 2
// 468.718 us; speedup vs baseline: 6.0395x; 6.0395x over previous
//
#include <hip/hip_runtime.h>
#include <hip/hip_bf16.h>

typedef __attribute__((ext_vector_type(8))) short bf16x8;
typedef __attribute__((ext_vector_type(4))) float f32x4;
typedef __attribute__((ext_vector_type(4))) unsigned short u16x4;
typedef __attribute__((ext_vector_type(8))) unsigned short u16x8;

__device__ __forceinline__ unsigned short f2bf(float f) {
  unsigned u = __float_as_uint(f);
  u += 0x7FFF + ((u >> 16) & 1);   // RNE
  return (unsigned short)(u >> 16);
}
__device__ __forceinline__ float bf2f(unsigned short h) {
  return __uint_as_float(((unsigned)h) << 16);
}

__device__ __forceinline__ void gll16(const void* g, void* l) {
  __builtin_amdgcn_global_load_lds(
      (const __attribute__((address_space(1))) void*)g,
      (__attribute__((address_space(3))) void*)l, 16, 0, 0);
}

// ---------------------------------------------------------------------------
// bf16 MFMA GEMM:  C[bz] = A[bz] (MxK, k-inner) * B[bz]^T (B is [N][K], k-inner)
// 128x128 tile, BK=64, 4 waves (2x2 of 64x64), depth-2 prefetch, 3 LDS bufs.
// LDS tiles [128][64] bf16 (128B rows) with 8-slot XOR swizzle:
//   physical 16B slot = logical_slot ^ (row & 7)   (rule #21: linear dest,
//   inverse-swizzled global source, swizzled ds_read -> 2-way max aliasing).
// MODE 0: bf16 store.  MODE 1: per-COLUMN BN (bn=[4][N]) + ReLU, bf16 store.
// MODE 2: fp32 store.
// Requires M%128==0, N%128==0, K%64==0.
// ---------------------------------------------------------------------------
template <int MODE>
__global__ __launch_bounds__(256) void gemm_bf16(
    const unsigned short* __restrict__ A, long abs_,
    const unsigned short* __restrict__ B, long bbs,
    void* __restrict__ Cv, long cbs, int ldC,
    int M, int N, int K,
    const float* __restrict__ bn)
{
  __shared__ char smem[3 * 32768];   // 3 bufs x (A 16KB + B 16KB)
  const int tid = threadIdx.x;
  const int w = tid >> 6;
  const int lane = tid & 63;
  const int bz = blockIdx.z;
  const int m0 = blockIdx.y * 128;
  const int n0 = blockIdx.x * 128;
  const unsigned short* Ab = A + (long)bz * abs_;
  const unsigned short* Bb = B + (long)bz * bbs;

  const int rsub = lane >> 3;                 // row within 8-row group
  const int srcslot = (lane & 7) ^ rsub;      // inverse-swizzled source slot
  const int NT = K >> 6;

  auto stage = [&](int t, int buf) {
    const int k0 = t << 6;
    char* ab = smem + buf * 32768;
    char* bb = ab + 16384;
#pragma unroll
    for (int ii = 0; ii < 4; ++ii) {
      const int r = w * 32 + ii * 8;          // wave-uniform LDS row base
      gll16(Ab + (long)(m0 + r + rsub) * K + k0 + srcslot * 8, ab + r * 128);
    }
#pragma unroll
    for (int ii = 0; ii < 4; ++ii) {
      const int r = w * 32 + ii * 8;
      gll16(Bb + (long)(n0 + r + rsub) * K + k0 + srcslot * 8, bb + r * 128);
    }
  };

  f32x4 acc[4][4];
#pragma unroll
  for (int i = 0; i < 4; ++i)
#pragma unroll
    for (int j = 0; j < 4; ++j) acc[i][j] = (f32x4)0.f;

  const int wrb = (w >> 1) * 64;
  const int wcb = (w & 1) * 64;
  const int llo = lane & 15;
  const int lhi = lane >> 4;

  stage(0, 0);
  stage(1, 1);

  int cur = 0;
  for (int t = 0; t < NT; ++t) {
    if (t + 1 < NT) {
      asm volatile("s_waitcnt vmcnt(8)" ::: "memory");  // tile t landed, t+1 in flight
    } else {
      asm volatile("s_waitcnt vmcnt(0)" ::: "memory");
    }
    __builtin_amdgcn_s_barrier();
    asm volatile("" ::: "memory");
    if (t + 2 < NT) {
      int nb = cur + 2; if (nb >= 3) nb -= 3;
      stage(t + 2, nb);                       // overwrites tile t-1's buffer: safe post-barrier
    }
    char* ab = smem + cur * 32768;
    char* bb = ab + 16384;
#pragma unroll
    for (int kk = 0; kk < 2; ++kk) {
      const int sp = ((kk * 4 + lhi) ^ (llo & 7)) * 16;  // swizzled read slot
      bf16x8 af[4], bfr[4];
#pragma unroll
      for (int i = 0; i < 4; ++i)
        af[i] = *(const bf16x8*)(ab + (wrb + i * 16 + llo) * 128 + sp);
#pragma unroll
      for (int j = 0; j < 4; ++j)
        bfr[j] = *(const bf16x8*)(bb + (wcb + j * 16 + llo) * 128 + sp);
#pragma unroll
      for (int i = 0; i < 4; ++i)
#pragma unroll
        for (int j = 0; j < 4; ++j)
          acc[i][j] = __builtin_amdgcn_mfma_f32_16x16x32_bf16(af[i], bfr[j], acc[i][j], 0, 0, 0);
    }
    ++cur; if (cur == 3) cur = 0;
  }

  // epilogue: C/D frag mapping col = lane&15, row = (lane>>4)*4 + e  [m89-verified]
  const int gm = m0 + wrb + lhi * 4;
  const int gn = n0 + wcb + llo;
  if constexpr (MODE == 2) {
    float* Cb = (float*)Cv + (long)bz * cbs;
#pragma unroll
    for (int i = 0; i < 4; ++i)
#pragma unroll
      for (int j = 0; j < 4; ++j)
#pragma unroll
        for (int e = 0; e < 4; ++e)
          Cb[(long)(gm + i * 16 + e) * ldC + gn + j * 16] = acc[i][j][e];
  } else {
    unsigned short* Cb = (unsigned short*)Cv + (long)bz * cbs;
#pragma unroll
    for (int j = 0; j < 4; ++j) {
      const int col = gn + j * 16;
      float sc = 1.f, off = 0.f;
      if constexpr (MODE == 1) {
        float g = bn[col], bb2 = bn[N + col], mm = bn[2 * N + col], vv = bn[3 * N + col];
        sc = g / sqrtf(vv + 1e-5f);
        off = bb2 - mm * sc;
      }
#pragma unroll
      for (int i = 0; i < 4; ++i)
#pragma unroll
        for (int e = 0; e < 4; ++e) {
          float v = acc[i][j][e];
          if constexpr (MODE == 1) v = fmaxf(fmaf(v, sc, off), 0.f);
          Cb[(long)(gm + i * 16 + e) * ldC + col] = f2bf(v);
        }
    }
  }
}

// ---------------------------------------------------------------------------
// Row softmax in place on bf16 [rows][C=4096], one block per row, normalized.
// ---------------------------------------------------------------------------
__global__ __launch_bounds__(256) void softmax_row(unsigned short* __restrict__ E, int C)
{
  const long row = blockIdx.x;
  unsigned short* p = E + row * (long)C;
  const int tid = threadIdx.x;
  u16x8 u0 = *(const u16x8*)(p + tid * 16);
  u16x8 u1 = *(const u16x8*)(p + tid * 16 + 8);
  float v[16];
#pragma unroll
  for (int e = 0; e < 8; ++e) { v[e] = bf2f(u0[e]); v[8 + e] = bf2f(u1[e]); }
  float m = v[0];
#pragma unroll
  for (int e = 1; e < 16; ++e) m = fmaxf(m, v[e]);
#pragma unroll
  for (int o = 32; o >= 1; o >>= 1) m = fmaxf(m, __shfl_xor(m, o, 64));
  __shared__ float sm[4], ss[4];
  const int wv = tid >> 6, ln = tid & 63;
  if (ln == 0) sm[wv] = m;
  __syncthreads();
  m = fmaxf(fmaxf(sm[0], sm[1]), fmaxf(sm[2], sm[3]));
  float ev[16];
  float s = 0.f;
#pragma unroll
  for (int e = 0; e < 16; ++e) { ev[e] = __expf(v[e] - m); s += ev[e]; }
#pragma unroll
  for (int o = 32; o >= 1; o >>= 1) s += __shfl_xor(s, o, 64);
  if (ln == 0) ss[wv] = s;
  __syncthreads();
  s = ss[0] + ss[1] + ss[2] + ss[3];
  const float rs = 1.0f / s;
  u16x8 o0, o1;
#pragma unroll
  for (int e = 0; e < 8; ++e) { o0[e] = f2bf(ev[e] * rs); o1[e] = f2bf(ev[8 + e] * rs); }
  *(u16x8*)(p + tid * 16) = o0;
  *(u16x8*)(p + tid * 16 + 8) = o1;
}

// ---------------------------------------------------------------------------
// Transposes (64x64 LDS tiles) + f32->bf16 convert
// ---------------------------------------------------------------------------
__global__ __launch_bounds__(256) void tr_f32_bf16(
    const float* __restrict__ src, unsigned short* __restrict__ dst, int R, int C)
{
  __shared__ float t[64][65];
  const int c0 = blockIdx.x * 64, r0 = blockIdx.y * 64;
  const long bo = (long)blockIdx.z * R * C;
  const int tc = (threadIdx.x & 15) * 4;
  const int tr = threadIdx.x >> 4;
#pragma unroll
  for (int i = 0; i < 4; ++i) {
    const int r = tr + i * 16;
    float4 v = *(const float4*)&src[bo + (long)(r0 + r) * C + c0 + tc];
    t[r][tc] = v.x; t[r][tc + 1] = v.y; t[r][tc + 2] = v.z; t[r][tc + 3] = v.w;
  }
  __syncthreads();
#pragma unroll
  for (int i = 0; i < 4; ++i) {
    const int c = tr + i * 16;
    u16x4 o;
#pragma unroll
    for (int k = 0; k < 4; ++k) o[k] = f2bf(t[tc + k][c]);
    *(u16x4*)&dst[bo + (long)(c0 + c) * R + r0 + tc] = o;
  }
}

__global__ __launch_bounds__(256) void tr_bf16(
    const unsigned short* __restrict__ src, unsigned short* __restrict__ dst, int R, int C)
{
  __shared__ unsigned short t[64][68];
  const int c0 = blockIdx.x * 64, r0 = blockIdx.y * 64;
  const long bo = (long)blockIdx.z * R * C;
  const int tc = (threadIdx.x & 15) * 4;
  const int tr = threadIdx.x >> 4;
#pragma unroll
  for (int i = 0; i < 4; ++i) {
    const int r = tr + i * 16;
    u16x4 v = *(const u16x4*)&src[bo + (long)(r0 + r) * C + c0 + tc];
    t[r][tc] = v[0]; t[r][tc + 1] = v[1]; t[r][tc + 2] = v[2]; t[r][tc + 3] = v[3];
  }
  __syncthreads();
#pragma unroll
  for (int i = 0; i < 4; ++i) {
    const int c = tr + i * 16;
    u16x4 o;
#pragma unroll
    for (int k = 0; k < 4; ++k) o[k] = t[tc + k][c];
    *(u16x4*)&dst[bo + (long)(c0 + c) * R + r0 + tc] = o;
  }
}

__global__ __launch_bounds__(256) void cvt_bf16(
    const float* __restrict__ s, unsigned short* __restrict__ d, long n)
{
  long i = ((long)blockIdx.x * 256 + threadIdx.x) * 4;
  if (i >= n) return;
  float4 v = *(const float4*)(s + i);
  u16x4 o;
  o[0] = f2bf(v.x); o[1] = f2bf(v.y); o[2] = f2bf(v.z); o[3] = f2bf(v.w);
  *(u16x4*)(d + i) = o;
}

// ---------------------------------------------------------------------------
extern "C" void kernel_launch(void* const* d_in, const int* in_sizes, int n_in,
                              void* d_out, int out_size, void* d_ws, size_t ws_size,
                              hipStream_t stream)
{
  const int NB = 2, CIN = 2048, HW = 4096, RC = 512, CT = 4096;
  const float* x = (const float*)d_in[0];

  char* wsb = (char*)d_ws;
  unsigned short* xT      = (unsigned short*)wsb;                 // [NB][HW][CIN]  32MB
  unsigned short* redT    = (unsigned short*)(wsb + 33554432);    // [NB][HW][RC]    8MB
  unsigned short* red     = (unsigned short*)(wsb + 41943040);    // [NB][RC][HW]    8MB
  unsigned short* a1T     = (unsigned short*)(wsb + 50331648);    // [NB][HW][RC]    8MB
  unsigned short* logitsT = (unsigned short*)(wsb + 58720256);    // [NB][HW][CT]   64MB
  unsigned short* wredb   = (unsigned short*)(wsb + 125829120);   // [RC][CIN]       2MB
  unsigned short* w1b     = (unsigned short*)(wsb + 127926272);   // [RC][RC]      0.5MB
  unsigned short* w2b     = (unsigned short*)(wsb + 128450560);   // [CT][RC]        4MB

  // x [NB][CIN][HW] f32 -> xT [NB][HW][CIN] bf16 (once)
  tr_f32_bf16<<<dim3(HW / 64, CIN / 64, NB), 256, 0, stream>>>(x, xT, CIN, HW);

  for (int br = 0; br < 2; ++br) {
    const float* w_red = (const float*)d_in[1 + br * 5 + 0];
    const float* bn1f  = (const float*)d_in[1 + br * 5 + 1];
    const float* w1f   = (const float*)d_in[1 + br * 5 + 2];
    const float* bn2f  = (const float*)d_in[1 + br * 5 + 3];
    const float* w2f   = (const float*)d_in[1 + br * 5 + 4];

    cvt_bf16<<<dim3(1024), 256, 0, stream>>>(w_red, wredb, (long)RC * CIN);
    cvt_bf16<<<dim3(256),  256, 0, stream>>>(w1f,   w1b,   (long)RC * RC);
    cvt_bf16<<<dim3(2048), 256, 0, stream>>>(w2f,   w2b,   (long)CT * RC);

    // G1: redT[t][r] = relu(bn1(sum_k xT[t][k] * Wred[r][k]))   M=HW,N=RC,K=CIN
    gemm_bf16<1><<<dim3(RC / 128, HW / 128, NB), 256, 0, stream>>>(
        xT, (long)HW * CIN, wredb, 0, redT, (long)HW * RC, RC, HW, RC, CIN, bn1f);

    // red = transpose(redT)  -> [NB][RC][HW] (bmm A-operand)
    tr_bf16<<<dim3(RC / 64, HW / 64, NB), 256, 0, stream>>>(redT, red, HW, RC);

    // G2: a1T[t][r] = relu(bn2(sum_k redT[t][k] * W1[r][k]))    M=HW,N=RC,K=RC
    gemm_bf16<1><<<dim3(RC / 128, HW / 128, NB), 256, 0, stream>>>(
        redT, (long)HW * RC, w1b, 0, a1T, (long)HW * RC, RC, HW, RC, RC, bn2f);

    // G3: logitsT[t][c] = sum_k a1T[t][k] * W2[c][k]            M=HW,N=CT,K=RC
    gemm_bf16<0><<<dim3(CT / 128, HW / 128, NB), 256, 0, stream>>>(
        a1T, (long)HW * RC, w2b, 0, logitsT, (long)HW * CT, CT, HW, CT, RC, nullptr);

    // row softmax over c, normalized, in place -> E^T (the bmm B-operand)
    softmax_row<<<dim3(NB * HW), 256, 0, stream>>>(logitsT, CT);

    // G4: out[n][br*RC+r][t] = sum_k red[r][k] * ET[t][k]       M=RC,N=HW,K=CT
    gemm_bf16<2><<<dim3(HW / 128, RC / 128, NB), 256, 0, stream>>>(
        red, (long)RC * HW, logitsT, (long)HW * CT,
        (float*)d_out + (long)br * RC * HW, (long)2 * RC * HW, HW,
        RC, HW, CT, nullptr);
  }
}